// Round 1
// baseline (925.224 us; speedup 1.0000x reference)
//
#include <hip/hip_runtime.h>
#include <stdint.h>

#define LQ   4096
#define BQ   8
#define KNB  16
#define QPB  64     // queries per block
#define TPB  128    // threads per block (2 lanes per query)

typedef unsigned long long u64;

__global__ __launch_bounds__(TPB) void knn_kernel(
    const float4* __restrict__ frame4,   // (B, L, 3) float4 view of (B,L,4,3) floats
    float* __restrict__ out_e,           // (B, L, 16, 3)
    int* __restrict__ nbr_out)           // (B, L, 16)
{
    __shared__ float4 cpos[LQ];          // 64 KB: all centers of this batch (w = R00)

    const int b    = blockIdx.x >> 6;    // 64 blocks per batch
    const int qblk = blockIdx.x & 63;
    const int tid  = threadIdx.x;

    const float4* fb = frame4 + (size_t)b * LQ * 3;
    for (int j = tid; j < LQ; j += TPB) {
        cpos[j] = fb[j * 3];             // {cx, cy, cz, R00}
    }
    __syncthreads();

    const int qloc = tid >> 1;           // 0..63
    const int h    = tid & 1;            // candidate-half
    const int l    = qblk * QPB + qloc;  // within-batch query index
    const float4 me = cpos[l];

    // sorted ascending top-16 of u64 keys: (f32bits(d2) << 12) | j
    u64 K[KNB];
#pragma unroll
    for (int s = 0; s < KNB; ++s) K[s] = ~0ull;

    const int j0 = h * (LQ / 2);
#pragma unroll 4
    for (int jj = 0; jj < LQ / 2; ++jj) {
        const int j = j0 + jj;
        const float4 p = cpos[j];
        // bit-exact vs numpy: no FMA contraction, sum order (x^2 + y^2) + z^2
        const float dx = __fsub_rn(me.x, p.x);
        const float dy = __fsub_rn(me.y, p.y);
        const float dz = __fsub_rn(me.z, p.z);
        const float d  = __fadd_rn(__fadd_rn(__fmul_rn(dx, dx), __fmul_rn(dy, dy)),
                                   __fmul_rn(dz, dz));
        const u64 key = ((u64)__float_as_uint(d) << 12) | (unsigned)j;
        if (key < K[KNB - 1]) {
            // unrolled branch-free insertion (key < K[15] guaranteed)
            bool lt_cur = true;
#pragma unroll
            for (int s = KNB - 1; s >= 1; --s) {
                const u64 Km1 = K[s - 1];
                const bool lt_m1 = key < Km1;
                K[s] = lt_m1 ? Km1 : (lt_cur ? key : K[s]);
                lt_cur = lt_m1;
            }
            if (lt_cur) K[0] = key;
        }
    }

    // merge the two halves of this query (partner lane = lane^1)
    u64 P[KNB];
#pragma unroll
    for (int s = 0; s < KNB; ++s) P[s] = __shfl_xor(K[s], 1, 64);

    u64 M[KNB];
#pragma unroll
    for (int s = 0; s < KNB; ++s) {
        const u64 a = K[s], bb = P[KNB - 1 - s];
        M[s] = a < bb ? a : bb;          // half-cleaner: lowest 16, bitonic order
    }
    // bitonic merge -> fully sorted ascending
#pragma unroll
    for (int gap = 8; gap >= 1; gap >>= 1) {
#pragma unroll
        for (int s = 0; s < KNB; ++s) {
            if (!(s & gap)) {
                const u64 a = M[s], bb = M[s + gap];
                const bool sw = bb < a;
                M[s]       = sw ? bb : a;
                M[s + gap] = sw ? a : bb;
            }
        }
    }

    if (h == 0) {
        const size_t gq = (size_t)b * LQ + l;
        const float4 f1 = fb[l * 3 + 1];
        const float4 f2 = fb[l * 3 + 2];
        // R[c][r] = frame[b,l,1+c,r]; row layout: floats 3..11
        const float R00 = me.w, R01 = f1.x, R02 = f1.y;
        const float R10 = f1.z, R11 = f1.w, R12 = f2.x;
        const float R20 = f2.y, R21 = f2.z, R22 = f2.w;

        float ebuf[48];
        int   ibuf[16];
#pragma unroll
        for (int k = 0; k < KNB; ++k) {
            const int j = (int)(M[k] & 0xFFFu);
            ibuf[k] = j;
            const float4 p = cpos[j];
            const float dx = p.x - me.x;   // delta = nbr_center - center
            const float dy = p.y - me.y;
            const float dz = p.z - me.z;
            ebuf[k * 3 + 0] = dx * R00 + dy * R10 + dz * R20;
            ebuf[k * 3 + 1] = dx * R01 + dy * R11 + dz * R21;
            ebuf[k * 3 + 2] = dx * R02 + dy * R12 + dz * R22;
        }
        float4* eo = (float4*)(out_e + gq * 48);
#pragma unroll
        for (int t = 0; t < 12; ++t) eo[t] = ((const float4*)ebuf)[t];
        int4* no = (int4*)(nbr_out + gq * 16);
#pragma unroll
        for (int t = 0; t < 4; ++t) no[t] = ((const int4*)ibuf)[t];
    }
}

__global__ __launch_bounds__(256) void gather_kernel(
    const float4* __restrict__ attr4,    // (B, L, 32) float4
    const int* __restrict__ nbr,         // (B, L, 16)
    float4* __restrict__ outg4)          // (B, L, 16, 32) float4
{
    const int idx = blockIdx.x * 256 + threadIdx.x;   // 0 .. 16777215
    const int d4  = idx & 31;            // float4 within D=128
    const int blk = idx >> 5;            // (b*L + l)*16 + k
    const int b   = idx >> 21;           // / (L*16*32)
    const int nb  = nbr[blk];            // within-batch neighbor index
    outg4[idx] = attr4[(((size_t)b << 12) + (unsigned)nb) * 32 + d4];
}

extern "C" void kernel_launch(void* const* d_in, const int* in_sizes, int n_in,
                              void* d_out, int out_size, void* d_ws, size_t ws_size,
                              hipStream_t stream)
{
    const float* frame = (const float*)d_in[0];   // (8,4096,4,3) f32
    const float* attr  = (const float*)d_in[1];   // (8,4096,128) f32
    float* out = (float*)d_out;                   // euclidian (1572864) ++ gathered (67108864)
    int*   nbr = (int*)d_ws;                      // 2 MB scratch: (8,4096,16) int32

    knn_kernel<<<BQ * (LQ / QPB), TPB, 0, stream>>>((const float4*)frame, out, nbr);

    float4* outg4 = (float4*)(out + (size_t)BQ * LQ * KNB * 3);
    gather_kernel<<<(BQ * LQ * KNB * 128) / 4 / 256, 256, 0, stream>>>(
        (const float4*)attr, nbr, outg4);
}

// Round 3
// 498.969 us; speedup vs baseline: 1.8543x; 1.8543x over previous
//
#include <hip/hip_runtime.h>
#include <stdint.h>

typedef unsigned long long u64;
typedef float nfloat4 __attribute__((ext_vector_type(4)));  // native vec for nt-store

#define LQ   4096
#define BQ   8
#define KNB  16
#define LPQ  8                  // lanes per query
#define TPB  256
#define QPB  (TPB / LPQ)        // 32 queries per block
#define BPB  (LQ / QPB)         // 128 blocks per batch

__device__ __forceinline__ u64 umin64(u64 a, u64 b) { return a < b ? a : b; }

__global__ __launch_bounds__(TPB) void knn_kernel(
    const float4* __restrict__ frame4,   // (B, L, 3) float4 view of (B,L,4,3)
    float* __restrict__ out_e,           // (B, L, 16, 3)
    int* __restrict__ nbr_out)           // (B, L, 16)
{
    __shared__ float4 cpos[LQ];          // 64 KB: all centers of this batch (w = R00)

    const int b    = blockIdx.x >> 7;    // 128 blocks per batch
    const int qblk = blockIdx.x & (BPB - 1);
    const int tid  = threadIdx.x;

    const float4* fb = frame4 + (size_t)b * LQ * 3;
    for (int j = tid; j < LQ; j += TPB) cpos[j] = fb[j * 3];
    __syncthreads();

    const int qloc = tid >> 3;           // 0..31
    const int h    = tid & 7;            // candidate sub-stream
    const int l    = qblk * QPB + qloc;  // within-batch query index
    const float4 me = cpos[l];

    // running sorted-ascending top-16 of keys (f32bits(d2)<<12 | j)  (exact order)
    u64 R[KNB];
#pragma unroll
    for (int i = 0; i < KNB; ++i) R[i] = ~0ull;

#pragma unroll 1
    for (int bb = 0; bb < 32; ++bb) {
        // --- compute 16 candidate keys (lane h covers j = 128*bb + 8*t + h) ---
        u64 S[KNB];
#pragma unroll
        for (int t = 0; t < 16; ++t) {
            const int j = bb * 128 + t * 8 + h;
            const float4 p = cpos[j];
            // bit-exact vs numpy: no FMA contraction, sum order (x^2+y^2)+z^2
            const float dx = __fsub_rn(me.x, p.x);
            const float dy = __fsub_rn(me.y, p.y);
            const float dz = __fsub_rn(me.z, p.z);
            const float d  = __fadd_rn(__fadd_rn(__fmul_rn(dx, dx), __fmul_rn(dy, dy)),
                                       __fmul_rn(dz, dz));
            S[t] = ((u64)__float_as_uint(d) << 12) | (unsigned)j;
        }
        // --- bitonic sort S ascending (all indices compile-time) ---
#pragma unroll
        for (int k = 2; k <= 16; k <<= 1) {
#pragma unroll
            for (int g = k >> 1; g >= 1; g >>= 1) {
#pragma unroll
                for (int i = 0; i < 16; ++i) {
                    if ((i & g) == 0) {
                        const int j2 = i + g;
                        const bool up = ((i & k) == 0);
                        const u64 x = S[i], y = S[j2];
                        const bool sw = up ? (y < x) : (x < y);
                        S[i]  = sw ? y : x;
                        S[j2] = sw ? x : y;
                    }
                }
            }
        }
        // --- merge: 16 smallest of (R asc, S asc) -> R asc ---
        u64 M[KNB];
#pragma unroll
        for (int i = 0; i < 16; ++i) M[i] = umin64(R[i], S[15 - i]);  // bitonic
#pragma unroll
        for (int g = 8; g >= 1; g >>= 1) {
#pragma unroll
            for (int i = 0; i < 16; ++i) {
                if ((i & g) == 0) {
                    const u64 x = M[i], y = M[i + g];
                    const bool sw = y < x;
                    M[i]     = sw ? y : x;
                    M[i + g] = sw ? x : y;
                }
            }
        }
#pragma unroll
        for (int i = 0; i < 16; ++i) R[i] = M[i];
    }

    // --- cross-lane merge over the 8 sub-streams (xor 1,2,4) ---
#pragma unroll
    for (int m = 1; m <= 4; m <<= 1) {
        u64 P[KNB];
#pragma unroll
        for (int i = 0; i < 16; ++i) P[i] = __shfl_xor(R[i], m, 64);
        u64 M[KNB];
#pragma unroll
        for (int i = 0; i < 16; ++i) M[i] = umin64(R[i], P[15 - i]);
#pragma unroll
        for (int g = 8; g >= 1; g >>= 1) {
#pragma unroll
            for (int i = 0; i < 16; ++i) {
                if ((i & g) == 0) {
                    const u64 x = M[i], y = M[i + g];
                    const bool sw = y < x;
                    M[i]     = sw ? y : x;
                    M[i + g] = sw ? x : y;
                }
            }
        }
#pragma unroll
        for (int i = 0; i < 16; ++i) R[i] = M[i];
    }

    if (h == 0) {
        const size_t gq = (size_t)b * LQ + l;
        const float4 f1 = fb[l * 3 + 1];
        const float4 f2 = fb[l * 3 + 2];
        const float R00 = me.w, R01 = f1.x, R02 = f1.y;
        const float R10 = f1.z, R11 = f1.w, R12 = f2.x;
        const float R20 = f2.y, R21 = f2.z, R22 = f2.w;

        float ebuf[48];
        int   ibuf[16];
#pragma unroll
        for (int k = 0; k < KNB; ++k) {
            const int j = (int)(R[k] & 0xFFFu);
            ibuf[k] = j;
            const float4 p = cpos[j];
            const float dx = p.x - me.x;   // delta = nbr_center - center
            const float dy = p.y - me.y;
            const float dz = p.z - me.z;
            ebuf[k * 3 + 0] = dx * R00 + dy * R10 + dz * R20;
            ebuf[k * 3 + 1] = dx * R01 + dy * R11 + dz * R21;
            ebuf[k * 3 + 2] = dx * R02 + dy * R12 + dz * R22;
        }
        float4* eo = (float4*)(out_e + gq * 48);
#pragma unroll
        for (int t = 0; t < 12; ++t) eo[t] = ((const float4*)ebuf)[t];
        int4* no = (int4*)(nbr_out + gq * 16);
#pragma unroll
        for (int t = 0; t < 4; ++t) no[t] = ((const int4*)ibuf)[t];
    }
}

__global__ __launch_bounds__(256) void gather_kernel(
    const float4* __restrict__ attr4,    // (B, L, 32) float4
    const int* __restrict__ nbr,         // (B, L, 16)
    nfloat4* __restrict__ outg4)         // (B, L, 16, 32) float4
{
    const int idx = blockIdx.x * 256 + threadIdx.x;   // 0 .. 16777215
    const int d4  = idx & 31;            // float4 within D=128
    const int blk = idx >> 5;            // (b*L + l)*16 + k
    const int b   = idx >> 21;           // / (L*16*32)
    const int nb  = nbr[blk];            // within-batch neighbor index
    const float4 v = attr4[(((size_t)b << 12) + (unsigned)nb) * 32 + d4];
    nfloat4 nv = {v.x, v.y, v.z, v.w};
    __builtin_nontemporal_store(nv, &outg4[idx]);
}

extern "C" void kernel_launch(void* const* d_in, const int* in_sizes, int n_in,
                              void* d_out, int out_size, void* d_ws, size_t ws_size,
                              hipStream_t stream)
{
    const float* frame = (const float*)d_in[0];   // (8,4096,4,3) f32
    const float* attr  = (const float*)d_in[1];   // (8,4096,128) f32
    float* out = (float*)d_out;                   // euclidian (1572864) ++ gathered (67108864)
    int*   nbr = (int*)d_ws;                      // scratch: (8,4096,16) int32

    knn_kernel<<<BQ * BPB, TPB, 0, stream>>>((const float4*)frame, out, nbr);

    nfloat4* outg4 = (nfloat4*)(out + (size_t)BQ * LQ * KNB * 3);
    gather_kernel<<<(BQ * LQ * KNB * 128) / 4 / 256, 256, 0, stream>>>(
        (const float4*)attr, nbr, outg4);
}